// Round 8
// baseline (478.904 us; speedup 1.0000x reference)
//
#include <hip/hip_runtime.h>
#include <hip/hip_bf16.h>
#include <cstdint>
#include <cstddef>

#define S_FRAMES 32
#define P_TOK    196
#define H_HEADS  16
#define D_HEAD   64
#define C_DIM    1024
#define N_TOK    (S_FRAMES * P_TOK)   // 6272
#define MK_TOK   1960
#define LN_EPS   1e-6f
#define SM_SCALE 0.125f               // 1/sqrt(64)

typedef __attribute__((ext_vector_type(8))) short short8;
typedef __attribute__((ext_vector_type(4))) short short4v;
typedef __attribute__((ext_vector_type(4))) float f32x4;

static __device__ __forceinline__ ushort f2bf(float x) {
  union { float f; unsigned u; } c; c.f = x;
  unsigned r = (c.u + 0x7FFFu + ((c.u >> 16) & 1u)) >> 16;
  return (ushort)r;
}
static __device__ __forceinline__ float bf2f(ushort h) {
  union { unsigned u; float f; } c; c.u = ((unsigned)h) << 16;
  return c.f;
}
// packed f32->bf16x2 via HW instruction (lo = a, hi = b)
static __device__ __forceinline__ unsigned pack_cvt(float a, float b) {
  unsigned r;
  asm("v_cvt_pk_bf16_f32 %0, %1, %2" : "=v"(r) : "v"(a), "v"(b));
  return r;
}

// async global->LDS 16B per lane; LDS dest is wave-uniform base + lane*16
#define GLOAD16(g, l) __builtin_amdgcn_global_load_lds( \
    (const __attribute__((address_space(1))) void*)(g), \
    (__attribute__((address_space(3))) void*)(l), 16, 0, 0)

// ---------------------------------------------------------------------------
// W transpose + hi/lo split:  W [K][Nn] fp32  ->  Bth/Btl [Nn][K] bf16
// ---------------------------------------------------------------------------
__global__ __launch_bounds__(256) void wsplit_kernel(
    const float* __restrict__ W, ushort* __restrict__ Bth,
    ushort* __restrict__ Btl, int K, int Nn)
{
  __shared__ float T[64][72];
  const int n0 = blockIdx.x * 64;
  const int k0 = blockIdx.y * 64;
  const int tid = threadIdx.x;

  for (int idx = tid; idx < 64 * 16; idx += 256) {
    int r = idx >> 4, c4 = idx & 15;
    *(float4*)&T[r][c4 * 4] = *(const float4*)(W + (size_t)(k0 + r) * Nn + n0 + c4 * 4);
  }
  __syncthreads();
  for (int idx = tid; idx < 64 * 8; idx += 256) {
    int nr = idx >> 3, ch = idx & 7;
    short8 hi, lo;
    #pragma unroll
    for (int u = 0; u < 8; ++u) {
      float v = T[ch * 8 + u][nr];
      ushort h = f2bf(v);
      hi[u] = (short)h;
      lo[u] = (short)f2bf(v - bf2f(h));
    }
    *(short8*)(Bth + (size_t)(n0 + nr) * K + k0 + ch * 8) = hi;
    *(short8*)(Btl + (size_t)(n0 + nr) * K + k0 + ch * 8) = lo;
  }
}

// ---------------------------------------------------------------------------
// x split: x fp32 [N][K] -> Xh/Xl bf16 [N][K]
// ---------------------------------------------------------------------------
__global__ __launch_bounds__(256) void xsplit_kernel(
    const float* __restrict__ x, ushort* __restrict__ Xh,
    ushort* __restrict__ Xl, int n4)
{
  for (int i = blockIdx.x * 256 + threadIdx.x; i < n4; i += gridDim.x * 256) {
    float4 v = ((const float4*)x)[i];
    float vv[4] = {v.x, v.y, v.z, v.w};
    short4v h, lo;
    #pragma unroll
    for (int u = 0; u < 4; ++u) {
      ushort hb = f2bf(vv[u]);
      h[u] = (short)hb;
      lo[u] = (short)f2bf(vv[u] - bf2f(hb));
    }
    ((short4v*)Xh)[i] = h;
    ((short4v*)Xl)[i] = lo;
  }
}

// ---------------------------------------------------------------------------
// LPT schedule: count frames per s, sort descending -> order[32].
// Heavy (s) blocks dispatch first -> better makespan (round-6 lesson:
// OccupancyPercent 16.5% showed a long idle tail from 4..10-frame variance).
// ---------------------------------------------------------------------------
__global__ void sched_kernel(const float* __restrict__ ab, int* __restrict__ order)
{
  __shared__ int cnt[32];
  __shared__ int idxs[32];
  const int t = threadIdx.x;
  if (t < 32) {
    int c = 0;
    for (int f = 0; f < 10; ++f) {
      if (ab[(size_t)t * MK_TOK + f * P_TOK] < -1.0e8f) break;
      ++c;
    }
    cnt[t] = c;
    idxs[t] = t;
  }
  __syncthreads();
  if (t == 0) {
    for (int i = 0; i < 31; ++i) {
      int best = i;
      for (int j = i + 1; j < 32; ++j)
        if (cnt[idxs[j]] > cnt[idxs[best]]) best = j;
      int tmp = idxs[i]; idxs[i] = idxs[best]; idxs[best] = tmp;
    }
    for (int i = 0; i < 32; ++i) order[i] = idxs[i];
  }
}

// ---------------------------------------------------------------------------
// Split-bf16 3-product MFMA GEMM (unchanged from round 6)
// ---------------------------------------------------------------------------
template <int EMODE>
__global__ __launch_bounds__(256, 2) void gemm_split3(
    const ushort* __restrict__ Ah_g, const ushort* __restrict__ Al_g,
    const ushort* __restrict__ Bth, const ushort* __restrict__ Btl,
    const float* __restrict__ bias, float* __restrict__ Cout,
    ushort* __restrict__ Qb, ushort* __restrict__ Kb, ushort* __restrict__ Vtg,
    const float* __restrict__ qg, const float* __restrict__ qbet,
    const float* __restrict__ kg, const float* __restrict__ kbet,
    int M, int Nn, int K)
{
  __shared__ ushort Ah[128 * 64];
  __shared__ ushort Al[128 * 64];
  __shared__ ushort Bh[128 * 64];
  __shared__ ushort Bl[128 * 64];

  const int tid  = threadIdx.x;
  const int wave = tid >> 6;
  const int lane = tid & 63;
  const int g    = lane >> 4;
  const int lq   = lane & 15;
  const int bm   = blockIdx.y * 128;
  const int bn   = blockIdx.x * 128;
  const int wm   = (wave >> 1) * 64;
  const int wn   = (wave & 1) * 64;

  size_t offA[4], offB[4];
  unsigned ldsoff[4];
  #pragma unroll
  for (int i = 0; i < 4; ++i) {
    const int tr = wave * 8 + i * 32 + (lane >> 3);
    const int gc = (lane & 7) ^ (tr & 7);
    offA[i] = (size_t)(bm + tr) * K + gc * 8;
    offB[i] = (size_t)(bn + tr) * K + gc * 8;
    ldsoff[i] = (unsigned)(wave * 512 + i * 2048);
  }

  f32x4 acc[4][4];
  #pragma unroll
  for (int i = 0; i < 4; ++i)
    #pragma unroll
    for (int j = 0; j < 4; ++j) {
      acc[i][j][0] = 0.f; acc[i][j][1] = 0.f;
      acc[i][j][2] = 0.f; acc[i][j][3] = 0.f;
    }

  for (int k0 = 0; k0 < K; k0 += 64) {
    __syncthreads();
    #pragma unroll
    for (int i = 0; i < 4; ++i) {
      GLOAD16(Ah_g + offA[i] + k0, &Ah[ldsoff[i]]);
      GLOAD16(Al_g + offA[i] + k0, &Al[ldsoff[i]]);
      GLOAD16(Bth  + offB[i] + k0, &Bh[ldsoff[i]]);
      GLOAD16(Btl  + offB[i] + k0, &Bl[ldsoff[i]]);
    }
    __syncthreads();

    #pragma unroll
    for (int kt = 0; kt < 2; ++kt) {
      short8 ah[4], al[4], bh[4], bl[4];
      #pragma unroll
      for (int mi = 0; mi < 4; ++mi) {
        const int row = wm + mi * 16 + lq;
        const int sl = (kt * 4 + g) ^ (row & 7);
        ah[mi] = *(const short8*)&Ah[row * 64 + sl * 8];
        al[mi] = *(const short8*)&Al[row * 64 + sl * 8];
      }
      #pragma unroll
      for (int ni = 0; ni < 4; ++ni) {
        const int row = wn + ni * 16 + lq;
        const int sl = (kt * 4 + g) ^ (row & 7);
        bh[ni] = *(const short8*)&Bh[row * 64 + sl * 8];
        bl[ni] = *(const short8*)&Bl[row * 64 + sl * 8];
      }
      #pragma unroll
      for (int mi = 0; mi < 4; ++mi)
        #pragma unroll
        for (int ni = 0; ni < 4; ++ni) {
          acc[mi][ni] = __builtin_amdgcn_mfma_f32_16x16x32_bf16(ah[mi], bl[ni], acc[mi][ni], 0, 0, 0);
          acc[mi][ni] = __builtin_amdgcn_mfma_f32_16x16x32_bf16(al[mi], bh[ni], acc[mi][ni], 0, 0, 0);
          acc[mi][ni] = __builtin_amdgcn_mfma_f32_16x16x32_bf16(ah[mi], bh[ni], acc[mi][ni], 0, 0, 0);
        }
    }
  }

  const int col0 = bn + wn;
  float bias4[4];
  #pragma unroll
  for (int ni = 0; ni < 4; ++ni) bias4[ni] = bias[col0 + ni * 16 + lq];

  if (EMODE == 0) {
    #pragma unroll
    for (int mi = 0; mi < 4; ++mi)
      #pragma unroll
      for (int r = 0; r < 4; ++r) {
        float* cp = Cout + (size_t)(bm + wm + mi * 16 + g * 4 + r) * Nn + col0;
        #pragma unroll
        for (int ni = 0; ni < 4; ++ni)
          cp[ni * 16 + lq] = acc[mi][ni][r] + bias4[ni];
      }
  } else {
    const int type = col0 >> 10;              // 0=q 1=k 2=v
    const int h    = (col0 & 1023) >> 6;
    if (type < 2) {
      const float* gam = type ? kg : qg;
      const float* bet = type ? kbet : qbet;
      float gm[4], bt[4];
      #pragma unroll
      for (int ni = 0; ni < 4; ++ni) {
        gm[ni] = gam[ni * 16 + lq];
        bt[ni] = bet[ni * 16 + lq];
      }
      ushort* outb = (type ? Kb : Qb);
      #pragma unroll
      for (int mi = 0; mi < 4; ++mi)
        #pragma unroll
        for (int r = 0; r < 4; ++r) {
          float xv[4];
          float s = 0.f;
          #pragma unroll
          for (int ni = 0; ni < 4; ++ni) {
            xv[ni] = acc[mi][ni][r] + bias4[ni];
            s += xv[ni];
          }
          s += __shfl_xor(s, 1, 64);
          s += __shfl_xor(s, 2, 64);
          s += __shfl_xor(s, 4, 64);
          s += __shfl_xor(s, 8, 64);
          const float mu = s * (1.0f / 64.0f);
          float ss = 0.f;
          #pragma unroll
          for (int ni = 0; ni < 4; ++ni) {
            float dd = xv[ni] - mu;
            ss += dd * dd;
          }
          ss += __shfl_xor(ss, 1, 64);
          ss += __shfl_xor(ss, 2, 64);
          ss += __shfl_xor(ss, 4, 64);
          ss += __shfl_xor(ss, 8, 64);
          const float rs = rsqrtf(ss * (1.0f / 64.0f) + LN_EPS);
          const int tok = bm + wm + mi * 16 + g * 4 + r;
          ushort* op = outb + ((size_t)h * N_TOK + tok) * 64;
          #pragma unroll
          for (int ni = 0; ni < 4; ++ni)
            op[ni * 16 + lq] = f2bf((xv[ni] - mu) * rs * gm[ni] + bt[ni]);
        }
    } else {
      #pragma unroll
      for (int mi = 0; mi < 4; ++mi) {
        const int tok = bm + wm + mi * 16 + g * 4;
        #pragma unroll
        for (int ni = 0; ni < 4; ++ni) {
          const int d = ni * 16 + lq;
          short4v w;
          #pragma unroll
          for (int r = 0; r < 4; ++r) w[r] = (short)f2bf(acc[mi][ni][r] + bias4[ni]);
          *(short4v*)&Vtg[((size_t)(h * 64 + d)) * N_TOK + tok] = w;
        }
      }
    }
  }
}

// ---------------------------------------------------------------------------
// MFMA sparse attention. Block = (order[s-rank], h), 512 threads = 8 waves.
// Round-7: LPT block order; Q frags hoisted out of frame loop; Pl double-
// buffered; HW cvt_pk pack; kv-mask only in last kt2 (wave-uniform).
// ---------------------------------------------------------------------------
__global__ __launch_bounds__(512, 2) void attn_mfma_kernel(
    const ushort* __restrict__ Qb, const ushort* __restrict__ Kb,
    const ushort* __restrict__ Vtg,
    const int* __restrict__ gather_idx, const float* __restrict__ attn_bias,
    const int* __restrict__ order,
    ushort* __restrict__ Chi, ushort* __restrict__ Clo)
{
  constexpr int KROWS = 208;
  constexpr int VROW  = 232;
  constexpr int PROW  = 40;
  __shared__ ushort Ks[KROWS * 64];
  __shared__ ushort Vs[64 * VROW];
  __shared__ ushort Pl[8][2][16 * PROW];

  const int s = order[blockIdx.x >> 4];
  const int h = blockIdx.x & 15;
  const int tid = threadIdx.x;
  const int wave = tid >> 6;
  const int lane = tid & 63;
  const int g  = lane >> 4;
  const int lq = lane & 15;
  const int nq = (wave < 5) ? 2 : 1;

  const float KEXP = 0.18033688011112042f;   // SM_SCALE * log2(e)
  const float BEXP = 11.541560327111708f;    // 8 * log2(e)

  // one-time zero of pad regions (K rows 196..207, V cols >=196)
  for (int c = tid; c < (KROWS - P_TOK) * 8; c += 512) {
    const int row = P_TOK + (c >> 3), ch = c & 7;
    short8 z = {0,0,0,0,0,0,0,0};
    *(short8*)&Ks[row * 64 + (ch << 3)] = z;
  }
  for (int c = tid; c < 64 * 7; c += 512) {
    const int d = c / 7, ch = 49 + (c % 7);
    short4v z = {0,0,0,0};
    *(short4v*)&Vs[d * VROW + (ch << 2)] = z;
  }

  // hoist Q fragments (frame-invariant)
  short8 qf0[2], qf1[2];
  #pragma unroll 2
  for (int t = 0; t < 2; ++t) {
    if (t >= nq) break;
    const int qt = wave + t * 8;
    int qrow = qt * 16 + lq; if (qrow > P_TOK - 1) qrow = P_TOK - 1;
    const ushort* qbase = Qb + ((size_t)h * N_TOK + s * P_TOK + qrow) * 64 + g * 8;
    qf0[t] = *(const short8*)(qbase);
    qf1[t] = *(const short8*)(qbase + 32);
  }

  f32x4 oacc[2][4];
  #pragma unroll
  for (int t = 0; t < 2; ++t)
    #pragma unroll
    for (int dt = 0; dt < 4; ++dt) {
      oacc[t][dt][0] = 0.f; oacc[t][dt][1] = 0.f;
      oacc[t][dt][2] = 0.f; oacc[t][dt][3] = 0.f;
    }
  float lsum[2] = {0.f, 0.f};

  for (int f = 0; f < 10; ++f) {
    if (attn_bias[(size_t)s * MK_TOK + f * P_TOK] < -1.0e8f) break;
    const int tok0 = gather_idx[(size_t)s * MK_TOK + f * P_TOK];
    __syncthreads();

    for (int c = tid; c < P_TOK * 8; c += 512) {
      const int row = c >> 3, ch = c & 7;
      *(short8*)&Ks[row * 64 + ((ch ^ (row & 7)) << 3)] =
          *(const short8*)(Kb + ((size_t)h * N_TOK + tok0 + row) * 64 + (ch << 3));
    }
    for (int c = tid; c < 64 * 49; c += 512) {
      const int d = c / 49, ch = c - d * 49;
      *(short4v*)&Vs[d * VROW + (ch << 2)] =
          *(const short4v*)(Vtg + ((size_t)(h * 64 + d)) * N_TOK + tok0 + (ch << 2));
    }
    __syncthreads();

    #pragma unroll 2
    for (int t = 0; t < 2; ++t) {
      if (t >= nq) break;

      for (int kt2 = 0; kt2 < 7; ++kt2) {
        const int pbuf = kt2 & 1;
        #pragma unroll
        for (int half = 0; half < 2; ++half) {
          const int kt = kt2 * 2 + half;
          f32x4 sacc = {0.f, 0.f, 0.f, 0.f};
          if (kt < 13) {
            const int row = kt * 16 + lq;
            const int sw = row & 7;
            short8 ka0 = *(const short8*)&Ks[row * 64 + ((g ^ sw) << 3)];
            short8 ka1 = *(const short8*)&Ks[row * 64 + (((4 + g) ^ sw) << 3)];
            sacc = __builtin_amdgcn_mfma_f32_16x16x32_bf16(ka0, qf0[t], sacc, 0, 0, 0);
            sacc = __builtin_amdgcn_mfma_f32_16x16x32_bf16(ka1, qf1[t], sacc, 0, 0, 0);
          }
          float p[4];
          #pragma unroll
          for (int r = 0; r < 4; ++r)
            p[r] = __builtin_exp2f(fmaf(sacc[r], KEXP, -BEXP));
          if (kt2 == 6) {            // only tiles 12/13 contain padded kv
            #pragma unroll
            for (int r = 0; r < 4; ++r)
              if (kt * 16 + g * 4 + r >= P_TOK) p[r] = 0.f;
          }
          lsum[t] += (p[0] + p[1]) + (p[2] + p[3]);
          ushort* pw = &Pl[wave][pbuf][lq * PROW + half * 16 + g * 4];
          *(unsigned*)(pw)     = pack_cvt(p[0], p[1]);
          *(unsigned*)(pw + 2) = pack_cvt(p[2], p[3]);
        }
        const short8 pa = *(const short8*)&Pl[wave][pbuf][lq * PROW + g * 8];
        #pragma unroll
        for (int dt = 0; dt < 4; ++dt) {
          const short8 vb = *(const short8*)&Vs[(dt * 16 + lq) * VROW + kt2 * 32 + g * 8];
          oacc[t][dt] = __builtin_amdgcn_mfma_f32_16x16x32_bf16(pa, vb, oacc[t][dt], 0, 0, 0);
        }
      }
    }
  }

  #pragma unroll 2
  for (int t = 0; t < 2; ++t) {
    if (t >= nq) break;
    const int qt = wave + t * 8;
    float lv = lsum[t];
    lv += __shfl_xor(lv, 16, 64);
    lv += __shfl_xor(lv, 32, 64);
    #pragma unroll
    for (int r = 0; r < 4; ++r) {
      const int qrow = qt * 16 + g * 4 + r;
      const float lr = __shfl(lv, (lane & 48) | (g * 4 + r), 64);
      const float inv = 1.0f / lr;
      if (qrow < P_TOK) {
        const size_t rowb = ((size_t)(s * P_TOK + qrow)) * C_DIM + h * 64;
        #pragma unroll
        for (int dt = 0; dt < 4; ++dt) {
          float val = oacc[t][dt][r] * inv;
          ushort hi = f2bf(val);
          Chi[rowb + dt * 16 + lq] = hi;
          Clo[rowb + dt * 16 + lq] = f2bf(val - bf2f(hi));
        }
      }
    }
  }
}

// ---------------------------------------------------------------------------
// FALLBACK path (fp32, round-2) if workspace is too small
// ---------------------------------------------------------------------------
__global__ __launch_bounds__(256) void sgemm_bias_kernel(
    const float* __restrict__ A, const float* __restrict__ B,
    const float* __restrict__ bias, float* __restrict__ C,
    int M, int N, int K)
{
  constexpr int BM = 64, BN = 64, BK = 16;
  __shared__ alignas(16) float As[BK][BM + 4];
  __shared__ alignas(16) float Bs[BK][BN + 4];

  const int tid = threadIdx.x;
  const int bm = blockIdx.y * BM;
  const int bn = blockIdx.x * BN;
  const int tx = tid & 15;
  const int ty = tid >> 4;
  const int ar = tid >> 2;
  const int ak = (tid & 3) * 4;
  const int br = tid >> 4;
  const int bc = (tid & 15) * 4;

  float acc[4][4] = {};

  for (int k0 = 0; k0 < K; k0 += BK) {
    __syncthreads();
    float4 av = *(const float4*)(A + (size_t)(bm + ar) * K + k0 + ak);
    As[ak + 0][ar] = av.x;
    As[ak + 1][ar] = av.y;
    As[ak + 2][ar] = av.z;
    As[ak + 3][ar] = av.w;
    *(float4*)&Bs[br][bc] = *(const float4*)(B + (size_t)(k0 + br) * N + bn + bc);
    __syncthreads();

    #pragma unroll
    for (int kk = 0; kk < BK; ++kk) {
      float4 a4 = *(const float4*)&As[kk][ty * 4];
      float4 b4 = *(const float4*)&Bs[kk][tx * 4];
      float aa[4] = {a4.x, a4.y, a4.z, a4.w};
      float bb[4] = {b4.x, b4.y, b4.z, b4.w};
      #pragma unroll
      for (int i = 0; i < 4; ++i)
        #pragma unroll
        for (int j = 0; j < 4; ++j)
          acc[i][j] = fmaf(aa[i], bb[j], acc[i][j]);
    }
  }

  #pragma unroll
  for (int i = 0; i < 4; ++i) {
    float4 o;
    o.x = acc[i][0] + bias[bn + tx * 4 + 0];
    o.y = acc[i][1] + bias[bn + tx * 4 + 1];
    o.z = acc[i][2] + bias[bn + tx * 4 + 2];
    o.w = acc[i][3] + bias[bn + tx * 4 + 3];
    *(float4*)(C + (size_t)(bm + ty * 4 + i) * N + bn + tx * 4) = o;
  }
}

__global__ __launch_bounds__(128) void qk_ln_kernel(
    float* __restrict__ qkv,
    const float* __restrict__ qg, const float* __restrict__ qb,
    const float* __restrict__ kg, const float* __restrict__ kb)
{
  const int r = blockIdx.x;
  const int n = r / H_HEADS;
  const int h = r % H_HEADS;
  const int wave = threadIdx.x >> 6;
  const int lane = threadIdx.x & 63;

  float* p = qkv + (size_t)n * (3 * C_DIM) + wave * C_DIM + h * D_HEAD + lane;
  float v = *p;
  float sum = v;
  #pragma unroll
  for (int off = 32; off; off >>= 1) sum += __shfl_xor(sum, off, 64);
  float mu = sum * (1.0f / 64.0f);
  float d = v - mu;
  float vs = d * d;
  #pragma unroll
  for (int off = 32; off; off >>= 1) vs += __shfl_xor(vs, off, 64);
  float var = vs * (1.0f / 64.0f);
  float rstd = rsqrtf(var + LN_EPS);
  const float* gg = wave ? kg : qg;
  const float* bb = wave ? kb : qb;
  *p = d * rstd * gg[lane] + bb[lane];
}

__global__ __launch_bounds__(256) void sparse_attn_kernel(
    const float* __restrict__ qkv,
    const int*   __restrict__ gather_idx,
    const float* __restrict__ attn_bias,
    float* __restrict__ attn_out)
{
  constexpr int KC = 64;
  __shared__ alignas(16) float Ksf[KC][D_HEAD + 4];
  __shared__ alignas(16) float Vsf[KC][D_HEAD + 4];
  __shared__ float biasS[KC];

  const int s = blockIdx.x >> 4;
  const int h = blockIdx.x & 15;
  const int tid = threadIdx.x;
  const int p = tid;
  const bool active = (p < P_TOK);

  const int*   gi = gather_idx + (size_t)s * MK_TOK;
  const float* bi = attn_bias + (size_t)s * MK_TOK;

  const int qrow = s * P_TOK + (active ? p : 0);
  const float* qptr = qkv + (size_t)qrow * (3 * C_DIM) + h * D_HEAD;
  float q[D_HEAD];
  #pragma unroll
  for (int c = 0; c < 16; ++c) {
    float4 t4 = *(const float4*)(qptr + 4 * c);
    q[4 * c + 0] = t4.x; q[4 * c + 1] = t4.y;
    q[4 * c + 2] = t4.z; q[4 * c + 3] = t4.w;
  }

  float m = -3.0e38f;
  float l = 0.0f;
  float acc[D_HEAD] = {};
  const int jld = tid & 63;
  const int cpart = tid >> 6;

  for (int j0 = 0; j0 < MK_TOK; j0 += KC) {
    const int jn = min(KC, MK_TOK - j0);
    __syncthreads();
    if (jld < jn) {
      const int idx = gi[j0 + jld];
      const float* kbp = qkv + (size_t)idx * (3 * C_DIM) + C_DIM + h * D_HEAD + cpart * 16;
      const float* vbp = kbp + C_DIM;
      #pragma unroll
      for (int u = 0; u < 4; ++u) {
        *(float4*)&Ksf[jld][cpart * 16 + 4 * u] = *(const float4*)(kbp + 4 * u);
        *(float4*)&Vsf[jld][cpart * 16 + 4 * u] = *(const float4*)(vbp + 4 * u);
      }
    }
    if (tid < jn) biasS[tid] = bi[j0 + tid];
    __syncthreads();

    for (int j = 0; j < jn; ++j) {
      float s0 = 0.f, s1 = 0.f, s2 = 0.f, s3 = 0.f;
      #pragma unroll
      for (int c = 0; c < 16; ++c) {
        float4 kv = *(const float4*)&Ksf[j][4 * c];
        s0 = fmaf(q[4 * c + 0], kv.x, s0);
        s1 = fmaf(q[4 * c + 1], kv.y, s1);
        s2 = fmaf(q[4 * c + 2], kv.z, s2);
        s3 = fmaf(q[4 * c + 3], kv.w, s3);
      }
      float sc = (s0 + s1) + (s2 + s3);
      sc = sc * SM_SCALE + biasS[j];
      if (sc > m) {
        float al = __expf(m - sc);
        l *= al;
        #pragma unroll
        for (int d = 0; d < D_HEAD; ++d) acc[d] *= al;
        m = sc;
      }
      float pe = __expf(sc - m);
      l += pe;
      #pragma unroll
      for (int c = 0; c < 16; ++c) {
        float4 vv = *(const float4*)&Vsf[j][4 * c];
        acc[4 * c + 0] = fmaf(pe, vv.x, acc[4 * c + 0]);
        acc[4 * c + 1] = fmaf(pe, vv.y, acc[4 * c + 1]);
        acc[4 * c + 2] = fmaf(pe, vv.z, acc[4 * c + 2]);
        acc[4 * c + 3] = fmaf(pe, vv.w, acc[4 * c + 3]);
      }
    }
  }

  if (active) {
    const float inv = 1.0f / l;
    float* op = attn_out + (size_t)(s * P_TOK + p) * C_DIM + h * D_HEAD;
    #pragma unroll
    for (int c = 0; c < 16; ++c) {
      float4 o;
      o.x = acc[4 * c + 0] * inv;
      o.y = acc[4 * c + 1] * inv;
      o.z = acc[4 * c + 2] * inv;
      o.w = acc[4 * c + 3] * inv;
      *(float4*)(op + 4 * c) = o;
    }
  }
}

// ---------------------------------------------------------------------------
extern "C" void kernel_launch(void* const* d_in, const int* in_sizes, int n_in,
                              void* d_out, int out_size, void* d_ws, size_t ws_size,
                              hipStream_t stream)
{
  const float* x      = (const float*)d_in[0];
  const float* W_qkv  = (const float*)d_in[1];
  const float* b_qkv  = (const float*)d_in[2];
  const float* q_g    = (const float*)d_in[3];
  const float* q_b    = (const float*)d_in[4];
  const float* k_g    = (const float*)d_in[5];
  const float* k_b    = (const float*)d_in[6];
  const float* W_proj = (const float*)d_in[7];
  const float* b_proj = (const float*)d_in[8];
  const int*   g_idx  = (const int*)d_in[9];
  const float* a_bias = (const float*)d_in[10];
  float* out = (float*)d_out;

  const size_t VS = (size_t)H_HEADS * D_HEAD * N_TOK;          // 6,422,528 elems
  const size_t WQ = (size_t)3 * C_DIM * C_DIM;
  const size_t WP = (size_t)C_DIM * C_DIM;
  const size_t need_new = (5 * VS + 2 * WQ + 2 * WP) * sizeof(ushort) + 256;

  if (ws_size >= need_new) {
    ushort* base = (ushort*)d_ws;
    ushort* Vtg  = base;
    ushort* Qb   = base + VS;
    ushort* Kb   = base + 2 * VS;
    ushort* Chi  = base + 3 * VS;    // also Xh before attention
    ushort* Clo  = base + 4 * VS;    // also Xl before attention
    ushort* WqT_h = base + 5 * VS;
    ushort* WqT_l = WqT_h + WQ;
    ushort* WpT_h = WqT_l + WQ;
    ushort* WpT_l = WpT_h + WP;
    int*    order = (int*)(WpT_l + WP);
    ushort* Xh = Chi;
    ushort* Xl = Clo;

    // 0) input splits + LPT schedule
    wsplit_kernel<<<dim3(48, 16), 256, 0, stream>>>(W_qkv, WqT_h, WqT_l, C_DIM, 3 * C_DIM);
    wsplit_kernel<<<dim3(16, 16), 256, 0, stream>>>(W_proj, WpT_h, WpT_l, C_DIM, C_DIM);
    xsplit_kernel<<<2048, 256, 0, stream>>>(x, Xh, Xl, N_TOK * C_DIM / 4);
    sched_kernel<<<1, 64, 0, stream>>>(a_bias, order);

    // 1) QKV GEMM + fused LN -> Qb/Kb, v -> Vtg
    gemm_split3<1><<<dim3(24, 49), 256, 0, stream>>>(
        Xh, Xl, WqT_h, WqT_l, b_qkv, nullptr,
        Qb, Kb, Vtg, q_g, q_b, k_g, k_b, N_TOK, 3 * C_DIM, C_DIM);

    // 2) attention -> Chi/Clo (overwrites Xh/Xl)
    attn_mfma_kernel<<<S_FRAMES * H_HEADS, 512, 0, stream>>>(
        Qb, Kb, Vtg, g_idx, a_bias, order, Chi, Clo);

    // 3) proj GEMM -> d_out fp32
    gemm_split3<0><<<dim3(8, 49), 256, 0, stream>>>(
        Chi, Clo, WpT_h, WpT_l, b_proj, out,
        nullptr, nullptr, nullptr, nullptr, nullptr, nullptr, nullptr,
        N_TOK, C_DIM, C_DIM);
  } else {
    // fp32 fallback (round-2 path)
    float* qkv      = (float*)d_ws;
    float* attn_out = qkv + (size_t)N_TOK * 3 * C_DIM;
    sgemm_bias_kernel<<<dim3((3 * C_DIM) / 64, N_TOK / 64), 256, 0, stream>>>(
        x, W_qkv, b_qkv, qkv, N_TOK, 3 * C_DIM, C_DIM);
    qk_ln_kernel<<<N_TOK * H_HEADS, 128, 0, stream>>>(qkv, q_g, q_b, k_g, k_b);
    sparse_attn_kernel<<<S_FRAMES * H_HEADS, 256, 0, stream>>>(
        qkv, g_idx, a_bias, attn_out);
    sgemm_bias_kernel<<<dim3(C_DIM / 64, N_TOK / 64), 256, 0, stream>>>(
        attn_out, W_proj, b_proj, out, N_TOK, C_DIM, C_DIM);
  }
}